// Round 1
// baseline (1026.711 us; speedup 1.0000x reference)
//
#include <hip/hip_runtime.h>
#include <hip/hip_bf16.h>
#include <math.h>

#define N_NODES 50000
#define N_EDGES 800000
#define E_TOT   (N_EDGES + N_NODES)
#define F_IN    64
#define HIDDEN  128
#define HEADS   4
#define OUT_DIM 256
#define N_GRAPHS 1024
#define BN_EPS  1e-5f
#define SLOPE   0.2f

// ---------------- CSR build ----------------

__global__ void hist_kernel(const int* __restrict__ ei, int* __restrict__ deg) {
    int i = blockIdx.x * blockDim.x + threadIdx.x;
    if (i >= E_TOT) return;
    int d = (i < N_EDGES) ? ei[N_EDGES + i] : (i - N_EDGES);
    atomicAdd(&deg[d], 1);
}

// single-block exclusive scan over N_NODES ints -> row_start[N_NODES+1]
__global__ void scan_kernel(const int* __restrict__ deg, int* __restrict__ row_start) {
    __shared__ int sdata[256];
    __shared__ int carry_s;
    int tid = threadIdx.x;
    if (tid == 0) carry_s = 0;
    __syncthreads();
    for (int base = 0; base < N_NODES; base += 256) {
        int i = base + tid;
        int v = (i < N_NODES) ? deg[i] : 0;
        sdata[tid] = v;
        __syncthreads();
        for (int off = 1; off < 256; off <<= 1) {
            int t = (tid >= off) ? sdata[tid - off] : 0;
            __syncthreads();
            sdata[tid] += t;
            __syncthreads();
        }
        int incl = sdata[tid];
        int carry = carry_s;
        if (i < N_NODES) row_start[i] = carry + incl - v;
        __syncthreads();
        if (tid == 255) carry_s = carry + incl;
        __syncthreads();
    }
    if (tid == 0) row_start[N_NODES] = carry_s;
}

__global__ void scatter_kernel(const int* __restrict__ ei, const int* __restrict__ row_start,
                               int* __restrict__ cursor, int* __restrict__ csr_src) {
    int i = blockIdx.x * blockDim.x + threadIdx.x;
    if (i >= E_TOT) return;
    int s, d;
    if (i < N_EDGES) { s = ei[i]; d = ei[N_EDGES + i]; }
    else             { s = i - N_EDGES; d = s; }
    int pos = atomicAdd(&cursor[d], 1);
    csr_src[row_start[d] + pos] = s;
}

// ---------------- fused GEMM + attention scores ----------------
// H[n,j] = sum_k X[n,k]*W[k,j];  es[n,h] = sum_c H[n,h*32+c]*a_src[h,c]; same ed.
// block = 256 threads = 2 nodes x 128 cols
__global__ void gemm_att_kernel(const float* __restrict__ X, const float* __restrict__ W,
                                const float* __restrict__ a_src, const float* __restrict__ a_dst,
                                float* __restrict__ H, float* __restrict__ es, float* __restrict__ ed,
                                int Fin) {
    int tid = threadIdx.x;
    int n = blockIdx.x * 2 + (tid >> 7);
    int j = tid & 127;
    if (n >= N_NODES) return;
    const float* xr = X + (size_t)n * Fin;
    float acc = 0.f;
    for (int k = 0; k < Fin; k += 4) {
        acc += xr[k]     * W[(k)   * HIDDEN + j];
        acc += xr[k + 1] * W[(k+1) * HIDDEN + j];
        acc += xr[k + 2] * W[(k+2) * HIDDEN + j];
        acc += xr[k + 3] * W[(k+3) * HIDDEN + j];
    }
    H[(size_t)n * HIDDEN + j] = acc;
    float vs = acc * a_src[j];
    float vd = acc * a_dst[j];
    for (int off = 16; off; off >>= 1) {
        vs += __shfl_xor(vs, off, 32);
        vd += __shfl_xor(vd, off, 32);
    }
    if ((j & 31) == 0) {
        es[n * HEADS + (j >> 5)] = vs;
        ed[n * HEADS + (j >> 5)] = vd;
    }
}

// ---------------- per-node GAT aggregation (1 wave / node, no atomics) ----------------
// out[n,j] = (sum_e exp(lrelu(es[src]+ed[n])) * H[src,j]) / (sum_e exp(...)) + bias[j]
__global__ void gat_aggregate_kernel(const float* __restrict__ H, const float* __restrict__ es,
                                     const float* __restrict__ ed, const int* __restrict__ row_start,
                                     const int* __restrict__ csr_src, const float* __restrict__ bias,
                                     float* __restrict__ out) {
    int lane = threadIdx.x & 63;
    int n = blockIdx.x * 4 + (threadIdx.x >> 6);
    if (n >= N_NODES) return;
    int hid = lane >> 4;                 // head for channels 2*lane, 2*lane+1
    float edn = ed[n * HEADS + hid];
    int k0 = row_start[n], k1 = row_start[n + 1];
    float dsum = 0.f, accx = 0.f, accy = 0.f;
    for (int k = k0; k < k1; ++k) {
        int s = csr_src[k];
        float e = es[s * HEADS + hid] + edn;
        e = (e > 0.f) ? e : (SLOPE * e);
        float ex = __expf(e);
        dsum += ex;
        const float2 hv = *reinterpret_cast<const float2*>(H + (size_t)s * HIDDEN + 2 * lane);
        accx += ex * hv.x;
        accy += ex * hv.y;
    }
    float inv = 1.f / (dsum + 1e-16f);
    int j = 2 * lane;
    out[(size_t)n * HIDDEN + j]     = accx * inv + bias[j];
    out[(size_t)n * HIDDEN + j + 1] = accy * inv + bias[j + 1];
}

// ---------------- BatchNorm (2-pass) + ELU ----------------
__global__ void bn_stats_kernel(const float* __restrict__ X, float* __restrict__ stats) {
    int c = threadIdx.x & 127;
    int r0 = blockIdx.x * 2 + (threadIdx.x >> 7);
    float s = 0.f, s2 = 0.f;
    for (int n = r0; n < N_NODES; n += gridDim.x * 2) {
        float v = X[(size_t)n * HIDDEN + c];
        s += v;
        s2 += v * v;
    }
    atomicAdd(&stats[c], s);
    atomicAdd(&stats[HIDDEN + c], s2);
}

__global__ void bn_apply_kernel(float* __restrict__ X, const float* __restrict__ stats,
                                const float* __restrict__ g, const float* __restrict__ b) {
    const float invN = 1.f / (float)N_NODES;
    int i = blockIdx.x * blockDim.x + threadIdx.x;
    const int total = N_NODES * HIDDEN;
    for (; i < total; i += gridDim.x * blockDim.x) {
        int c = i & 127;
        float mu = stats[c] * invN;
        float var = stats[HIDDEN + c] * invN - mu * mu;
        float v = (X[i] - mu) * rsqrtf(var + BN_EPS) * g[c] + b[c];
        X[i] = (v > 0.f) ? v : expm1f(v);
    }
}

// ---------------- global mean pool ----------------
__global__ void pool_kernel(const float* __restrict__ X, const int* __restrict__ batch,
                            float* __restrict__ psum, float* __restrict__ pcnt) {
    int i = blockIdx.x * blockDim.x + threadIdx.x;
    const int total = N_NODES * HIDDEN;
    for (; i < total; i += gridDim.x * blockDim.x) {
        int n = i >> 7, c = i & 127;
        int gidx = batch[n];
        atomicAdd(&psum[gidx * HIDDEN + c], X[i]);
        if (c == 0) atomicAdd(&pcnt[gidx], 1.0f);
    }
}

// ---------------- final linear ----------------
__global__ void final_kernel(const float* __restrict__ psum, const float* __restrict__ pcnt,
                             const float* __restrict__ Wlin, const float* __restrict__ blin,
                             float* __restrict__ out) {
    int idx = blockIdx.x * blockDim.x + threadIdx.x;   // N_GRAPHS*OUT_DIM
    int g = idx >> 8, o = idx & 255;
    float invc = 1.f / fmaxf(pcnt[g], 1.f);
    float acc = blin[o];
    const float* pr = psum + g * HIDDEN;
    for (int j = 0; j < HIDDEN; ++j)
        acc += pr[j] * invc * Wlin[j * OUT_DIM + o];
    out[idx] = acc;
}

// ---------------- launch ----------------

extern "C" void kernel_launch(void* const* d_in, const int* in_sizes, int n_in,
                              void* d_out, int out_size, void* d_ws, size_t ws_size,
                              hipStream_t stream) {
    const float* x    = (const float*)d_in[0];
    const int*   ei   = (const int*)d_in[1];
    const int*   batch= (const int*)d_in[2];
    const float* W1   = (const float*)d_in[3];
    const float* as1  = (const float*)d_in[4];
    const float* ad1  = (const float*)d_in[5];
    const float* b1   = (const float*)d_in[6];
    const float* W2   = (const float*)d_in[7];
    const float* as2  = (const float*)d_in[8];
    const float* ad2  = (const float*)d_in[9];
    const float* b2   = (const float*)d_in[10];
    const float* bn1g = (const float*)d_in[11];
    const float* bn1b = (const float*)d_in[12];
    const float* bn2g = (const float*)d_in[13];
    const float* bn2b = (const float*)d_in[14];
    const float* Wlin = (const float*)d_in[15];
    const float* blin = (const float*)d_in[16];
    float* out = (float*)d_out;

    char* ws = (char*)d_ws;
    const size_t SZ_H = (size_t)N_NODES * HIDDEN * 4;     // 25.6 MB
    float* A        = (float*)(ws);                       // h buffer A
    float* B        = (float*)(ws + SZ_H);                // h buffer B
    size_t off = 2 * SZ_H;
    float* es       = (float*)(ws + off); off += (size_t)N_NODES * HEADS * 4;
    float* ed       = (float*)(ws + off); off += (size_t)N_NODES * HEADS * 4;
    int*   row_start= (int*)(ws + off);   off += ((size_t)(N_NODES + 1) * 4 + 511) & ~511ull;
    int*   csr_src  = (int*)(ws + off);   off += ((size_t)E_TOT * 4 + 511) & ~511ull;
    // ---- zeroed region starts here ----
    size_t zoff = off;
    int*   deg      = (int*)(ws + off);   off += (size_t)N_NODES * 4;
    int*   cursor   = (int*)(ws + off);   off += (size_t)N_NODES * 4;
    float* stats1   = (float*)(ws + off); off += 2 * HIDDEN * 4;
    float* stats2   = (float*)(ws + off); off += 2 * HIDDEN * 4;
    float* psum     = (float*)(ws + off); off += (size_t)N_GRAPHS * HIDDEN * 4;
    float* pcnt     = (float*)(ws + off); off += (size_t)N_GRAPHS * 4;
    size_t zbytes = off - zoff;
    (void)ws_size; (void)n_in; (void)in_sizes; (void)out_size;

    hipMemsetAsync(ws + zoff, 0, zbytes, stream);

    const int TB = 256;
    const int egrid = (E_TOT + TB - 1) / TB;

    // CSR build (shared by both layers)
    hist_kernel<<<egrid, TB, 0, stream>>>(ei, deg);
    scan_kernel<<<1, TB, 0, stream>>>(deg, row_start);
    scatter_kernel<<<egrid, TB, 0, stream>>>(ei, row_start, cursor, csr_src);

    // ---- layer 1 ----
    gemm_att_kernel<<<N_NODES / 2, TB, 0, stream>>>(x, W1, as1, ad1, A, es, ed, F_IN);
    gat_aggregate_kernel<<<N_NODES / 4, TB, 0, stream>>>(A, es, ed, row_start, csr_src, b1, B);
    bn_stats_kernel<<<512, TB, 0, stream>>>(B, stats1);
    bn_apply_kernel<<<2048, TB, 0, stream>>>(B, stats1, bn1g, bn1b);

    // ---- layer 2 ----
    gemm_att_kernel<<<N_NODES / 2, TB, 0, stream>>>(B, W2, as2, ad2, A, es, ed, HIDDEN);
    gat_aggregate_kernel<<<N_NODES / 4, TB, 0, stream>>>(A, es, ed, row_start, csr_src, b2, B);
    bn_stats_kernel<<<512, TB, 0, stream>>>(B, stats2);
    bn_apply_kernel<<<2048, TB, 0, stream>>>(B, stats2, bn2g, bn2b);

    // ---- pool + linear ----
    pool_kernel<<<2048, TB, 0, stream>>>(B, batch, psum, pcnt);
    final_kernel<<<(N_GRAPHS * OUT_DIM) / TB, TB, 0, stream>>>(psum, pcnt, Wlin, blin, out);
}

// Round 2
// 818.669 us; speedup vs baseline: 1.2541x; 1.2541x over previous
//
#include <hip/hip_runtime.h>
#include <hip/hip_bf16.h>
#include <math.h>

#define N_NODES 50000
#define N_EDGES 800000
#define E_TOT   (N_EDGES + N_NODES)
#define F_IN    64
#define HIDDEN  128
#define HEADS   4
#define OUT_DIM 256
#define N_GRAPHS 1024
#define BN_EPS  1e-5f
#define SLOPE   0.2f

#define SCAN_TILE 2048                      // 256 threads x 8 elems
#define N_TILES   ((N_NODES + SCAN_TILE - 1) / SCAN_TILE)   // 25

// ---------------- CSR build ----------------

__global__ void hist_kernel(const int* __restrict__ ei, int* __restrict__ deg) {
    int i = blockIdx.x * blockDim.x + threadIdx.x;
    if (i >= E_TOT) return;
    int d = (i < N_EDGES) ? ei[N_EDGES + i] : (i - N_EDGES);
    atomicAdd(&deg[d], 1);
}

// phase 1: per-tile sums
__global__ void scan_partial_kernel(const int* __restrict__ deg, int* __restrict__ tile_sums) {
    __shared__ int wsum[4];
    int tile = blockIdx.x;
    int tid = threadIdx.x;
    int base = tile * SCAN_TILE + tid * 8;
    int s = 0;
    #pragma unroll
    for (int k = 0; k < 8; ++k) {
        int i = base + k;
        if (i < N_NODES) s += deg[i];
    }
    int lane = tid & 63;
    for (int off = 1; off < 64; off <<= 1) s += __shfl_xor(s, off, 64);
    if (lane == 0) wsum[tid >> 6] = s;
    __syncthreads();
    if (tid == 0) tile_sums[tile] = wsum[0] + wsum[1] + wsum[2] + wsum[3];
}

// phase 2: exclusive scan of N_TILES (25) values — trivially serial
__global__ void scan_tilesums_kernel(const int* __restrict__ tile_sums, int* __restrict__ tile_off) {
    if (threadIdx.x == 0) {
        int acc = 0;
        for (int t = 0; t < N_TILES; ++t) { tile_off[t] = acc; acc += tile_sums[t]; }
    }
}

// phase 3: per-tile scan, emit row_start
__global__ void scan_apply_kernel(const int* __restrict__ deg, const int* __restrict__ tile_off,
                                  int* __restrict__ row_start) {
    __shared__ int wsum[4];
    int tile = blockIdx.x;
    int tid = threadIdx.x;
    int lane = tid & 63;
    int wid = tid >> 6;
    int base = tile * SCAN_TILE + tid * 8;
    int v[8];
    int tsum = 0;
    #pragma unroll
    for (int k = 0; k < 8; ++k) {
        int i = base + k;
        v[k] = (i < N_NODES) ? deg[i] : 0;
        tsum += v[k];
    }
    // inclusive wave scan of thread sums
    int sc = tsum;
    for (int off = 1; off < 64; off <<= 1) {
        int t = __shfl_up(sc, off, 64);
        if (lane >= off) sc += t;
    }
    if (lane == 63) wsum[wid] = sc;
    __syncthreads();
    int woff = 0;
    for (int w = 0; w < 4; ++w) woff += (w < wid) ? wsum[w] : 0;
    __syncthreads();
    int toff = tile_off[tile] + woff + (sc - tsum);   // exclusive offset for this thread
    #pragma unroll
    for (int k = 0; k < 8; ++k) {
        int i = base + k;
        if (i < N_NODES) row_start[i] = toff;
        toff += v[k];
    }
    if (tile == 0 && tid == 0) row_start[N_NODES] = E_TOT;
}

__global__ void scatter_kernel(const int* __restrict__ ei, const int* __restrict__ row_start,
                               int* __restrict__ cursor, int* __restrict__ csr_src) {
    int i = blockIdx.x * blockDim.x + threadIdx.x;
    if (i >= E_TOT) return;
    int s, d;
    if (i < N_EDGES) { s = ei[i]; d = ei[N_EDGES + i]; }
    else             { s = i - N_EDGES; d = s; }
    int pos = atomicAdd(&cursor[d], 1);
    csr_src[row_start[d] + pos] = s;
}

// ---------------- fused GEMM + attention scores ----------------
__global__ void gemm_att_kernel(const float* __restrict__ X, const float* __restrict__ W,
                                const float* __restrict__ a_src, const float* __restrict__ a_dst,
                                float* __restrict__ H, float* __restrict__ es, float* __restrict__ ed,
                                int Fin) {
    int tid = threadIdx.x;
    int n = blockIdx.x * 2 + (tid >> 7);
    int j = tid & 127;
    if (n >= N_NODES) return;
    const float* xr = X + (size_t)n * Fin;
    float acc = 0.f;
    for (int k = 0; k < Fin; k += 4) {
        acc += xr[k]     * W[(k)   * HIDDEN + j];
        acc += xr[k + 1] * W[(k+1) * HIDDEN + j];
        acc += xr[k + 2] * W[(k+2) * HIDDEN + j];
        acc += xr[k + 3] * W[(k+3) * HIDDEN + j];
    }
    H[(size_t)n * HIDDEN + j] = acc;
    float vs = acc * a_src[j];
    float vd = acc * a_dst[j];
    for (int off = 16; off; off >>= 1) {
        vs += __shfl_xor(vs, off, 32);
        vd += __shfl_xor(vd, off, 32);
    }
    if ((j & 31) == 0) {
        es[n * HEADS + (j >> 5)] = vs;
        ed[n * HEADS + (j >> 5)] = vd;
    }
}

// ---------------- per-node GAT aggregation (1 wave / node, no atomics) ----------------
__global__ void gat_aggregate_kernel(const float* __restrict__ H, const float* __restrict__ es,
                                     const float* __restrict__ ed, const int* __restrict__ row_start,
                                     const int* __restrict__ csr_src, const float* __restrict__ bias,
                                     float* __restrict__ out) {
    int lane = threadIdx.x & 63;
    int n = blockIdx.x * 4 + (threadIdx.x >> 6);
    if (n >= N_NODES) return;
    int hid = lane >> 4;
    float edn = ed[n * HEADS + hid];
    int k0 = row_start[n], k1 = row_start[n + 1];
    float dsum = 0.f, accx = 0.f, accy = 0.f;
    for (int k = k0; k < k1; ++k) {
        int s = csr_src[k];
        float e = es[s * HEADS + hid] + edn;
        e = (e > 0.f) ? e : (SLOPE * e);
        float ex = __expf(e);
        dsum += ex;
        const float2 hv = *reinterpret_cast<const float2*>(H + (size_t)s * HIDDEN + 2 * lane);
        accx += ex * hv.x;
        accy += ex * hv.y;
    }
    float inv = 1.f / (dsum + 1e-16f);
    int j = 2 * lane;
    out[(size_t)n * HIDDEN + j]     = accx * inv + bias[j];
    out[(size_t)n * HIDDEN + j + 1] = accy * inv + bias[j + 1];
}

// ---------------- BatchNorm (2-pass) + ELU ----------------
__global__ void bn_stats_kernel(const float* __restrict__ X, float* __restrict__ stats) {
    int c = threadIdx.x & 127;
    int r0 = blockIdx.x * 2 + (threadIdx.x >> 7);
    float s = 0.f, s2 = 0.f;
    for (int n = r0; n < N_NODES; n += gridDim.x * 2) {
        float v = X[(size_t)n * HIDDEN + c];
        s += v;
        s2 += v * v;
    }
    atomicAdd(&stats[c], s);
    atomicAdd(&stats[HIDDEN + c], s2);
}

__global__ void bn_apply_kernel(float* __restrict__ X, const float* __restrict__ stats,
                                const float* __restrict__ g, const float* __restrict__ b) {
    const float invN = 1.f / (float)N_NODES;
    int i = blockIdx.x * blockDim.x + threadIdx.x;
    const int total = N_NODES * HIDDEN;
    for (; i < total; i += gridDim.x * blockDim.x) {
        int c = i & 127;
        float mu = stats[c] * invN;
        float var = stats[HIDDEN + c] * invN - mu * mu;
        float v = (X[i] - mu) * rsqrtf(var + BN_EPS) * g[c] + b[c];
        X[i] = (v > 0.f) ? v : expm1f(v);
    }
}

// ---------------- global mean pool ----------------
__global__ void pool_kernel(const float* __restrict__ X, const int* __restrict__ batch,
                            float* __restrict__ psum, float* __restrict__ pcnt) {
    int i = blockIdx.x * blockDim.x + threadIdx.x;
    const int total = N_NODES * HIDDEN;
    for (; i < total; i += gridDim.x * blockDim.x) {
        int n = i >> 7, c = i & 127;
        int gidx = batch[n];
        atomicAdd(&psum[gidx * HIDDEN + c], X[i]);
        if (c == 0) atomicAdd(&pcnt[gidx], 1.0f);
    }
}

// ---------------- final linear ----------------
__global__ void final_kernel(const float* __restrict__ psum, const float* __restrict__ pcnt,
                             const float* __restrict__ Wlin, const float* __restrict__ blin,
                             float* __restrict__ out) {
    int idx = blockIdx.x * blockDim.x + threadIdx.x;
    int g = idx >> 8, o = idx & 255;
    float invc = 1.f / fmaxf(pcnt[g], 1.f);
    float acc = blin[o];
    const float* pr = psum + g * HIDDEN;
    for (int j = 0; j < HIDDEN; ++j)
        acc += pr[j] * invc * Wlin[j * OUT_DIM + o];
    out[idx] = acc;
}

// ---------------- launch ----------------

extern "C" void kernel_launch(void* const* d_in, const int* in_sizes, int n_in,
                              void* d_out, int out_size, void* d_ws, size_t ws_size,
                              hipStream_t stream) {
    const float* x    = (const float*)d_in[0];
    const int*   ei   = (const int*)d_in[1];
    const int*   batch= (const int*)d_in[2];
    const float* W1   = (const float*)d_in[3];
    const float* as1  = (const float*)d_in[4];
    const float* ad1  = (const float*)d_in[5];
    const float* b1   = (const float*)d_in[6];
    const float* W2   = (const float*)d_in[7];
    const float* as2  = (const float*)d_in[8];
    const float* ad2  = (const float*)d_in[9];
    const float* b2   = (const float*)d_in[10];
    const float* bn1g = (const float*)d_in[11];
    const float* bn1b = (const float*)d_in[12];
    const float* bn2g = (const float*)d_in[13];
    const float* bn2b = (const float*)d_in[14];
    const float* Wlin = (const float*)d_in[15];
    const float* blin = (const float*)d_in[16];
    float* out = (float*)d_out;

    char* ws = (char*)d_ws;
    const size_t SZ_H = (size_t)N_NODES * HIDDEN * 4;     // 25.6 MB
    float* A        = (float*)(ws);
    float* B        = (float*)(ws + SZ_H);
    size_t off = 2 * SZ_H;
    float* es       = (float*)(ws + off); off += (size_t)N_NODES * HEADS * 4;
    float* ed       = (float*)(ws + off); off += (size_t)N_NODES * HEADS * 4;
    int*   row_start= (int*)(ws + off);   off += ((size_t)(N_NODES + 1) * 4 + 511) & ~511ull;
    int*   csr_src  = (int*)(ws + off);   off += ((size_t)E_TOT * 4 + 511) & ~511ull;
    int*   tile_sums= (int*)(ws + off);   off += ((size_t)N_TILES * 4 + 511) & ~511ull;
    int*   tile_off = (int*)(ws + off);   off += ((size_t)N_TILES * 4 + 511) & ~511ull;
    // ---- zeroed region starts here ----
    size_t zoff = off;
    int*   deg      = (int*)(ws + off);   off += (size_t)N_NODES * 4;
    int*   cursor   = (int*)(ws + off);   off += (size_t)N_NODES * 4;
    float* stats1   = (float*)(ws + off); off += 2 * HIDDEN * 4;
    float* stats2   = (float*)(ws + off); off += 2 * HIDDEN * 4;
    float* psum     = (float*)(ws + off); off += (size_t)N_GRAPHS * HIDDEN * 4;
    float* pcnt     = (float*)(ws + off); off += (size_t)N_GRAPHS * 4;
    size_t zbytes = off - zoff;
    (void)ws_size; (void)n_in; (void)in_sizes; (void)out_size;

    hipMemsetAsync(ws + zoff, 0, zbytes, stream);

    const int TB = 256;
    const int egrid = (E_TOT + TB - 1) / TB;

    // CSR build (shared by both layers)
    hist_kernel<<<egrid, TB, 0, stream>>>(ei, deg);
    scan_partial_kernel<<<N_TILES, TB, 0, stream>>>(deg, tile_sums);
    scan_tilesums_kernel<<<1, 64, 0, stream>>>(tile_sums, tile_off);
    scan_apply_kernel<<<N_TILES, TB, 0, stream>>>(deg, tile_off, row_start);
    scatter_kernel<<<egrid, TB, 0, stream>>>(ei, row_start, cursor, csr_src);

    // ---- layer 1 ----
    gemm_att_kernel<<<N_NODES / 2, TB, 0, stream>>>(x, W1, as1, ad1, A, es, ed, F_IN);
    gat_aggregate_kernel<<<N_NODES / 4, TB, 0, stream>>>(A, es, ed, row_start, csr_src, b1, B);
    bn_stats_kernel<<<512, TB, 0, stream>>>(B, stats1);
    bn_apply_kernel<<<2048, TB, 0, stream>>>(B, stats1, bn1g, bn1b);

    // ---- layer 2 ----
    gemm_att_kernel<<<N_NODES / 2, TB, 0, stream>>>(B, W2, as2, ad2, A, es, ed, HIDDEN);
    gat_aggregate_kernel<<<N_NODES / 4, TB, 0, stream>>>(A, es, ed, row_start, csr_src, b2, B);
    bn_stats_kernel<<<512, TB, 0, stream>>>(B, stats2);
    bn_apply_kernel<<<2048, TB, 0, stream>>>(B, stats2, bn2g, bn2b);

    // ---- pool + linear ----
    pool_kernel<<<2048, TB, 0, stream>>>(B, batch, psum, pcnt);
    final_kernel<<<(N_GRAPHS * OUT_DIM) / TB, TB, 0, stream>>>(psum, pcnt, Wlin, blin, out);
}

// Round 3
// 638.787 us; speedup vs baseline: 1.6073x; 1.2816x over previous
//
#include <hip/hip_runtime.h>
#include <hip/hip_bf16.h>
#include <math.h>

#define N_NODES 50000
#define N_EDGES 800000
#define E_TOT   (N_EDGES + N_NODES)
#define F_IN    64
#define HIDDEN  128
#define HEADS   4
#define OUT_DIM 256
#define N_GRAPHS 1024
#define BN_EPS  1e-5f
#define SLOPE   0.2f

#define SCAN_TILE 2048
#define N_TILES   ((N_NODES + SCAN_TILE - 1) / SCAN_TILE)   // 25

// ---------------- CSR build ----------------

__global__ void hist_kernel(const int* __restrict__ ei, int* __restrict__ deg) {
    int i = blockIdx.x * blockDim.x + threadIdx.x;
    if (i >= E_TOT) return;
    int d = (i < N_EDGES) ? ei[N_EDGES + i] : (i - N_EDGES);
    atomicAdd(&deg[d], 1);
}

__global__ void scan_partial_kernel(const int* __restrict__ deg, int* __restrict__ tile_sums) {
    __shared__ int wsum[4];
    int tile = blockIdx.x;
    int tid = threadIdx.x;
    int base = tile * SCAN_TILE + tid * 8;
    int s = 0;
    #pragma unroll
    for (int k = 0; k < 8; ++k) {
        int i = base + k;
        if (i < N_NODES) s += deg[i];
    }
    int lane = tid & 63;
    for (int off = 1; off < 64; off <<= 1) s += __shfl_xor(s, off, 64);
    if (lane == 0) wsum[tid >> 6] = s;
    __syncthreads();
    if (tid == 0) tile_sums[tile] = wsum[0] + wsum[1] + wsum[2] + wsum[3];
}

__global__ void scan_tilesums_kernel(const int* __restrict__ tile_sums, int* __restrict__ tile_off) {
    if (threadIdx.x == 0) {
        int acc = 0;
        for (int t = 0; t < N_TILES; ++t) { tile_off[t] = acc; acc += tile_sums[t]; }
    }
}

__global__ void scan_apply_kernel(const int* __restrict__ deg, const int* __restrict__ tile_off,
                                  int* __restrict__ row_start) {
    __shared__ int wsum[4];
    int tile = blockIdx.x;
    int tid = threadIdx.x;
    int lane = tid & 63;
    int wid = tid >> 6;
    int base = tile * SCAN_TILE + tid * 8;
    int v[8];
    int tsum = 0;
    #pragma unroll
    for (int k = 0; k < 8; ++k) {
        int i = base + k;
        v[k] = (i < N_NODES) ? deg[i] : 0;
        tsum += v[k];
    }
    int sc = tsum;
    for (int off = 1; off < 64; off <<= 1) {
        int t = __shfl_up(sc, off, 64);
        if (lane >= off) sc += t;
    }
    if (lane == 63) wsum[wid] = sc;
    __syncthreads();
    int woff = 0;
    for (int w = 0; w < 4; ++w) woff += (w < wid) ? wsum[w] : 0;
    __syncthreads();
    int toff = tile_off[tile] + woff + (sc - tsum);
    #pragma unroll
    for (int k = 0; k < 8; ++k) {
        int i = base + k;
        if (i < N_NODES) row_start[i] = toff;
        toff += v[k];
    }
    if (tile == 0 && tid == 0) row_start[N_NODES] = E_TOT;
}

__global__ void scatter_kernel(const int* __restrict__ ei, const int* __restrict__ row_start,
                               int* __restrict__ cursor, int* __restrict__ csr_src) {
    int i = blockIdx.x * blockDim.x + threadIdx.x;
    if (i >= E_TOT) return;
    int s, d;
    if (i < N_EDGES) { s = ei[i]; d = ei[N_EDGES + i]; }
    else             { s = i - N_EDGES; d = s; }
    int pos = atomicAdd(&cursor[d], 1);
    csr_src[row_start[d] + pos] = s;
}

// ---------------- register-tiled GEMM + attention scores ----------------
// block = 256 threads; 32 nodes/block. thread -> node pair np = tid>>4, col group cg = tid&15
// each thread: 2 nodes x 8 cols (16 accumulators)
template<int FIN>
__global__ __launch_bounds__(256) void gemm_att_kernel(
        const float* __restrict__ X, const float* __restrict__ W,
        const float* __restrict__ a_src, const float* __restrict__ a_dst,
        float* __restrict__ H, float* __restrict__ es, float* __restrict__ ed) {
    int tid = threadIdx.x;
    int cg = tid & 15;
    int np = tid >> 4;
    int n0 = blockIdx.x * 32 + np * 2;
    int n1 = n0 + 1;
    int j0 = cg * 8;
    bool ok0 = n0 < N_NODES, ok1 = n1 < N_NODES;
    const float* x0 = X + (size_t)(ok0 ? n0 : 0) * FIN;
    const float* x1 = X + (size_t)(ok1 ? n1 : 0) * FIN;
    float acc0[8] = {0,0,0,0,0,0,0,0};
    float acc1[8] = {0,0,0,0,0,0,0,0};
    #pragma unroll 2
    for (int k = 0; k < FIN; k += 4) {
        float4 a0 = *reinterpret_cast<const float4*>(x0 + k);
        float4 a1 = *reinterpret_cast<const float4*>(x1 + k);
        #pragma unroll
        for (int kk = 0; kk < 4; ++kk) {
            const float* wr = W + (size_t)(k + kk) * HIDDEN + j0;
            float4 wa = *reinterpret_cast<const float4*>(wr);
            float4 wb = *reinterpret_cast<const float4*>(wr + 4);
            float av0 = (kk == 0) ? a0.x : (kk == 1) ? a0.y : (kk == 2) ? a0.z : a0.w;
            float av1 = (kk == 0) ? a1.x : (kk == 1) ? a1.y : (kk == 2) ? a1.z : a1.w;
            acc0[0] += av0 * wa.x; acc0[1] += av0 * wa.y; acc0[2] += av0 * wa.z; acc0[3] += av0 * wa.w;
            acc0[4] += av0 * wb.x; acc0[5] += av0 * wb.y; acc0[6] += av0 * wb.z; acc0[7] += av0 * wb.w;
            acc1[0] += av1 * wa.x; acc1[1] += av1 * wa.y; acc1[2] += av1 * wa.z; acc1[3] += av1 * wa.w;
            acc1[4] += av1 * wb.x; acc1[5] += av1 * wb.y; acc1[6] += av1 * wb.z; acc1[7] += av1 * wb.w;
        }
    }
    // write H
    if (ok0) {
        float4* hp = reinterpret_cast<float4*>(H + (size_t)n0 * HIDDEN + j0);
        hp[0] = make_float4(acc0[0], acc0[1], acc0[2], acc0[3]);
        hp[1] = make_float4(acc0[4], acc0[5], acc0[6], acc0[7]);
    }
    if (ok1) {
        float4* hp = reinterpret_cast<float4*>(H + (size_t)n1 * HIDDEN + j0);
        hp[0] = make_float4(acc1[0], acc1[1], acc1[2], acc1[3]);
        hp[1] = make_float4(acc1[4], acc1[5], acc1[6], acc1[7]);
    }
    // attention scores: head h = cg>>2; reduce across the 4 lanes of the head group
    float vs0 = 0.f, vd0 = 0.f, vs1 = 0.f, vd1 = 0.f;
    #pragma unroll
    for (int i = 0; i < 8; ++i) {
        float sa = a_src[j0 + i], da = a_dst[j0 + i];
        vs0 += acc0[i] * sa; vd0 += acc0[i] * da;
        vs1 += acc1[i] * sa; vd1 += acc1[i] * da;
    }
    vs0 += __shfl_xor(vs0, 1, 64); vs0 += __shfl_xor(vs0, 2, 64);
    vd0 += __shfl_xor(vd0, 1, 64); vd0 += __shfl_xor(vd0, 2, 64);
    vs1 += __shfl_xor(vs1, 1, 64); vs1 += __shfl_xor(vs1, 2, 64);
    vd1 += __shfl_xor(vd1, 1, 64); vd1 += __shfl_xor(vd1, 2, 64);
    if ((cg & 3) == 0) {
        int h = cg >> 2;
        if (ok0) { es[n0 * HEADS + h] = vs0; ed[n0 * HEADS + h] = vd0; }
        if (ok1) { es[n1 * HEADS + h] = vs1; ed[n1 * HEADS + h] = vd1; }
    }
}

// ---------------- per-node GAT aggregation (1 wave / node, no atomics) ----------------
__global__ void gat_aggregate_kernel(const float* __restrict__ H, const float* __restrict__ es,
                                     const float* __restrict__ ed, const int* __restrict__ row_start,
                                     const int* __restrict__ csr_src, const float* __restrict__ bias,
                                     float* __restrict__ out) {
    int lane = threadIdx.x & 63;
    int n = blockIdx.x * 4 + (threadIdx.x >> 6);
    if (n >= N_NODES) return;
    int hid = lane >> 4;
    float edn = ed[n * HEADS + hid];
    int k0 = row_start[n], k1 = row_start[n + 1];
    float dsum = 0.f, accx = 0.f, accy = 0.f;
    for (int k = k0; k < k1; ++k) {
        int s = csr_src[k];
        float e = es[s * HEADS + hid] + edn;
        e = (e > 0.f) ? e : (SLOPE * e);
        float ex = __expf(e);
        dsum += ex;
        const float2 hv = *reinterpret_cast<const float2*>(H + (size_t)s * HIDDEN + 2 * lane);
        accx += ex * hv.x;
        accy += ex * hv.y;
    }
    float inv = 1.f / (dsum + 1e-16f);
    int j = 2 * lane;
    out[(size_t)n * HIDDEN + j]     = accx * inv + bias[j];
    out[(size_t)n * HIDDEN + j + 1] = accy * inv + bias[j + 1];
}

// ---------------- BatchNorm (2-pass) + ELU ----------------
__global__ void bn_stats_kernel(const float* __restrict__ X, float* __restrict__ stats) {
    int c = threadIdx.x & 127;
    int r0 = blockIdx.x * 2 + (threadIdx.x >> 7);
    float s = 0.f, s2 = 0.f;
    for (int n = r0; n < N_NODES; n += gridDim.x * 2) {
        float v = X[(size_t)n * HIDDEN + c];
        s += v;
        s2 += v * v;
    }
    atomicAdd(&stats[c], s);
    atomicAdd(&stats[HIDDEN + c], s2);
}

__global__ void bn_apply_kernel(float* __restrict__ X, const float* __restrict__ stats,
                                const float* __restrict__ g, const float* __restrict__ b) {
    const float invN = 1.f / (float)N_NODES;
    int i = blockIdx.x * blockDim.x + threadIdx.x;
    const int total = N_NODES * HIDDEN;
    for (; i < total; i += gridDim.x * blockDim.x) {
        int c = i & 127;
        float mu = stats[c] * invN;
        float var = stats[HIDDEN + c] * invN - mu * mu;
        float v = (X[i] - mu) * rsqrtf(var + BN_EPS) * g[c] + b[c];
        X[i] = (v > 0.f) ? v : expm1f(v);
    }
}

// layer-2: BN+ELU fused directly into the pooling accumulation (B never written back)
__global__ void bn_apply_pool_kernel(const float* __restrict__ X, const float* __restrict__ stats,
                                     const float* __restrict__ g, const float* __restrict__ b,
                                     const int* __restrict__ batch,
                                     float* __restrict__ psum, float* __restrict__ pcnt) {
    const float invN = 1.f / (float)N_NODES;
    int i = blockIdx.x * blockDim.x + threadIdx.x;
    const int total = N_NODES * HIDDEN;
    for (; i < total; i += gridDim.x * blockDim.x) {
        int n = i >> 7, c = i & 127;
        float mu = stats[c] * invN;
        float var = stats[HIDDEN + c] * invN - mu * mu;
        float v = (X[i] - mu) * rsqrtf(var + BN_EPS) * g[c] + b[c];
        v = (v > 0.f) ? v : expm1f(v);
        int gidx = batch[n];
        atomicAdd(&psum[gidx * HIDDEN + c], v);
        if (c == 0) atomicAdd(&pcnt[gidx], 1.0f);
    }
}

// ---------------- final linear ----------------
__global__ void final_kernel(const float* __restrict__ psum, const float* __restrict__ pcnt,
                             const float* __restrict__ Wlin, const float* __restrict__ blin,
                             float* __restrict__ out) {
    int idx = blockIdx.x * blockDim.x + threadIdx.x;
    int g = idx >> 8, o = idx & 255;
    float invc = 1.f / fmaxf(pcnt[g], 1.f);
    float acc = blin[o];
    const float* pr = psum + g * HIDDEN;
    for (int j = 0; j < HIDDEN; ++j)
        acc += pr[j] * invc * Wlin[j * OUT_DIM + o];
    out[idx] = acc;
}

// ---------------- launch ----------------

extern "C" void kernel_launch(void* const* d_in, const int* in_sizes, int n_in,
                              void* d_out, int out_size, void* d_ws, size_t ws_size,
                              hipStream_t stream) {
    const float* x    = (const float*)d_in[0];
    const int*   ei   = (const int*)d_in[1];
    const int*   batch= (const int*)d_in[2];
    const float* W1   = (const float*)d_in[3];
    const float* as1  = (const float*)d_in[4];
    const float* ad1  = (const float*)d_in[5];
    const float* b1   = (const float*)d_in[6];
    const float* W2   = (const float*)d_in[7];
    const float* as2  = (const float*)d_in[8];
    const float* ad2  = (const float*)d_in[9];
    const float* b2   = (const float*)d_in[10];
    const float* bn1g = (const float*)d_in[11];
    const float* bn1b = (const float*)d_in[12];
    const float* bn2g = (const float*)d_in[13];
    const float* bn2b = (const float*)d_in[14];
    const float* Wlin = (const float*)d_in[15];
    const float* blin = (const float*)d_in[16];
    float* out = (float*)d_out;

    char* ws = (char*)d_ws;
    const size_t SZ_H = (size_t)N_NODES * HIDDEN * 4;
    float* A        = (float*)(ws);
    float* B        = (float*)(ws + SZ_H);
    size_t off = 2 * SZ_H;
    float* es       = (float*)(ws + off); off += (size_t)N_NODES * HEADS * 4;
    float* ed       = (float*)(ws + off); off += (size_t)N_NODES * HEADS * 4;
    int*   row_start= (int*)(ws + off);   off += ((size_t)(N_NODES + 1) * 4 + 511) & ~511ull;
    int*   csr_src  = (int*)(ws + off);   off += ((size_t)E_TOT * 4 + 511) & ~511ull;
    int*   tile_sums= (int*)(ws + off);   off += ((size_t)N_TILES * 4 + 511) & ~511ull;
    int*   tile_off = (int*)(ws + off);   off += ((size_t)N_TILES * 4 + 511) & ~511ull;
    size_t zoff = off;
    int*   deg      = (int*)(ws + off);   off += (size_t)N_NODES * 4;
    int*   cursor   = (int*)(ws + off);   off += (size_t)N_NODES * 4;
    float* stats1   = (float*)(ws + off); off += 2 * HIDDEN * 4;
    float* stats2   = (float*)(ws + off); off += 2 * HIDDEN * 4;
    float* psum     = (float*)(ws + off); off += (size_t)N_GRAPHS * HIDDEN * 4;
    float* pcnt     = (float*)(ws + off); off += (size_t)N_GRAPHS * 4;
    size_t zbytes = off - zoff;
    (void)ws_size; (void)n_in; (void)in_sizes; (void)out_size;

    hipMemsetAsync(ws + zoff, 0, zbytes, stream);

    const int TB = 256;
    const int egrid = (E_TOT + TB - 1) / TB;
    const int ggrid = (N_NODES + 31) / 32;

    // CSR build (shared by both layers)
    hist_kernel<<<egrid, TB, 0, stream>>>(ei, deg);
    scan_partial_kernel<<<N_TILES, TB, 0, stream>>>(deg, tile_sums);
    scan_tilesums_kernel<<<1, 64, 0, stream>>>(tile_sums, tile_off);
    scan_apply_kernel<<<N_TILES, TB, 0, stream>>>(deg, tile_off, row_start);
    scatter_kernel<<<egrid, TB, 0, stream>>>(ei, row_start, cursor, csr_src);

    // ---- layer 1 ----
    gemm_att_kernel<F_IN><<<ggrid, TB, 0, stream>>>(x, W1, as1, ad1, A, es, ed);
    gat_aggregate_kernel<<<N_NODES / 4, TB, 0, stream>>>(A, es, ed, row_start, csr_src, b1, B);
    bn_stats_kernel<<<512, TB, 0, stream>>>(B, stats1);
    bn_apply_kernel<<<2048, TB, 0, stream>>>(B, stats1, bn1g, bn1b);

    // ---- layer 2 ----
    gemm_att_kernel<HIDDEN><<<ggrid, TB, 0, stream>>>(B, W2, as2, ad2, A, es, ed);
    gat_aggregate_kernel<<<N_NODES / 4, TB, 0, stream>>>(A, es, ed, row_start, csr_src, b2, B);
    bn_stats_kernel<<<512, TB, 0, stream>>>(B, stats2);
    bn_apply_pool_kernel<<<2048, TB, 0, stream>>>(B, stats2, bn2g, bn2b, batch, psum, pcnt);

    // ---- final linear ----
    final_kernel<<<(N_GRAPHS * OUT_DIM) / TB, TB, 0, stream>>>(psum, pcnt, Wlin, blin, out);
}

// Round 4
// 562.019 us; speedup vs baseline: 1.8268x; 1.1366x over previous
//
#include <hip/hip_runtime.h>
#include <hip/hip_bf16.h>
#include <hip/hip_fp16.h>
#include <math.h>

#define N_NODES 50000
#define N_EDGES 800000
#define E_TOT   (N_EDGES + N_NODES)
#define F_IN    64
#define HIDDEN  128
#define HEADS   4
#define OUT_DIM 256
#define N_GRAPHS 1024
#define BN_EPS  1e-5f
#define SLOPE   0.2f

#define SCAN_TILE 2048
#define N_TILES   ((N_NODES + SCAN_TILE - 1) / SCAN_TILE)   // 25

// ---------------- CSR build ----------------

__global__ void hist_kernel(const int* __restrict__ ei, int* __restrict__ deg) {
    int i = blockIdx.x * blockDim.x + threadIdx.x;
    if (i >= E_TOT) return;
    int d = (i < N_EDGES) ? ei[N_EDGES + i] : (i - N_EDGES);
    atomicAdd(&deg[d], 1);
}

__global__ void scan_partial_kernel(const int* __restrict__ deg, int* __restrict__ tile_sums) {
    __shared__ int wsum[4];
    int tile = blockIdx.x;
    int tid = threadIdx.x;
    int base = tile * SCAN_TILE + tid * 8;
    int s = 0;
    #pragma unroll
    for (int k = 0; k < 8; ++k) {
        int i = base + k;
        if (i < N_NODES) s += deg[i];
    }
    int lane = tid & 63;
    for (int off = 1; off < 64; off <<= 1) s += __shfl_xor(s, off, 64);
    if (lane == 0) wsum[tid >> 6] = s;
    __syncthreads();
    if (tid == 0) tile_sums[tile] = wsum[0] + wsum[1] + wsum[2] + wsum[3];
}

__global__ void scan_tilesums_kernel(const int* __restrict__ tile_sums, int* __restrict__ tile_off) {
    if (threadIdx.x == 0) {
        int acc = 0;
        for (int t = 0; t < N_TILES; ++t) { tile_off[t] = acc; acc += tile_sums[t]; }
    }
}

__global__ void scan_apply_kernel(const int* __restrict__ deg, const int* __restrict__ tile_off,
                                  int* __restrict__ row_start) {
    __shared__ int wsum[4];
    int tile = blockIdx.x;
    int tid = threadIdx.x;
    int lane = tid & 63;
    int wid = tid >> 6;
    int base = tile * SCAN_TILE + tid * 8;
    int v[8];
    int tsum = 0;
    #pragma unroll
    for (int k = 0; k < 8; ++k) {
        int i = base + k;
        v[k] = (i < N_NODES) ? deg[i] : 0;
        tsum += v[k];
    }
    int sc = tsum;
    for (int off = 1; off < 64; off <<= 1) {
        int t = __shfl_up(sc, off, 64);
        if (lane >= off) sc += t;
    }
    if (lane == 63) wsum[wid] = sc;
    __syncthreads();
    int woff = 0;
    for (int w = 0; w < 4; ++w) woff += (w < wid) ? wsum[w] : 0;
    __syncthreads();
    int toff = tile_off[tile] + woff + (sc - tsum);
    #pragma unroll
    for (int k = 0; k < 8; ++k) {
        int i = base + k;
        if (i < N_NODES) row_start[i] = toff;
        toff += v[k];
    }
    if (tile == 0 && tid == 0) row_start[N_NODES] = E_TOT;
}

__global__ void scatter_kernel(const int* __restrict__ ei, const int* __restrict__ row_start,
                               int* __restrict__ cursor, int* __restrict__ csr_src) {
    int i = blockIdx.x * blockDim.x + threadIdx.x;
    if (i >= E_TOT) return;
    int s, d;
    if (i < N_EDGES) { s = ei[i]; d = ei[N_EDGES + i]; }
    else             { s = i - N_EDGES; d = s; }
    int pos = atomicAdd(&cursor[d], 1);
    csr_src[row_start[d] + pos] = s;
}

// ---------------- register-tiled GEMM + attention scores (H stored fp16) ----------------
template<int FIN>
__global__ __launch_bounds__(256) void gemm_att_kernel(
        const float* __restrict__ X, const float* __restrict__ W,
        const float* __restrict__ a_src, const float* __restrict__ a_dst,
        __half* __restrict__ H, float* __restrict__ es, float* __restrict__ ed) {
    int tid = threadIdx.x;
    int cg = tid & 15;
    int np = tid >> 4;
    int n0 = blockIdx.x * 32 + np * 2;
    int n1 = n0 + 1;
    int j0 = cg * 8;
    bool ok0 = n0 < N_NODES, ok1 = n1 < N_NODES;
    const float* x0 = X + (size_t)(ok0 ? n0 : 0) * FIN;
    const float* x1 = X + (size_t)(ok1 ? n1 : 0) * FIN;
    float acc0[8] = {0,0,0,0,0,0,0,0};
    float acc1[8] = {0,0,0,0,0,0,0,0};
    #pragma unroll 2
    for (int k = 0; k < FIN; k += 4) {
        float4 a0 = *reinterpret_cast<const float4*>(x0 + k);
        float4 a1 = *reinterpret_cast<const float4*>(x1 + k);
        #pragma unroll
        for (int kk = 0; kk < 4; ++kk) {
            const float* wr = W + (size_t)(k + kk) * HIDDEN + j0;
            float4 wa = *reinterpret_cast<const float4*>(wr);
            float4 wb = *reinterpret_cast<const float4*>(wr + 4);
            float av0 = (kk == 0) ? a0.x : (kk == 1) ? a0.y : (kk == 2) ? a0.z : a0.w;
            float av1 = (kk == 0) ? a1.x : (kk == 1) ? a1.y : (kk == 2) ? a1.z : a1.w;
            acc0[0] += av0 * wa.x; acc0[1] += av0 * wa.y; acc0[2] += av0 * wa.z; acc0[3] += av0 * wa.w;
            acc0[4] += av0 * wb.x; acc0[5] += av0 * wb.y; acc0[6] += av0 * wb.z; acc0[7] += av0 * wb.w;
            acc1[0] += av1 * wa.x; acc1[1] += av1 * wa.y; acc1[2] += av1 * wa.z; acc1[3] += av1 * wa.w;
            acc1[4] += av1 * wb.x; acc1[5] += av1 * wb.y; acc1[6] += av1 * wb.z; acc1[7] += av1 * wb.w;
        }
    }
    // write H (fp16 packed, one 16B store per node)
    union { __half2 h2[4]; float4 f4; } pk;
    if (ok0) {
        pk.h2[0] = __floats2half2_rn(acc0[0], acc0[1]);
        pk.h2[1] = __floats2half2_rn(acc0[2], acc0[3]);
        pk.h2[2] = __floats2half2_rn(acc0[4], acc0[5]);
        pk.h2[3] = __floats2half2_rn(acc0[6], acc0[7]);
        *reinterpret_cast<float4*>(H + (size_t)n0 * HIDDEN + j0) = pk.f4;
    }
    if (ok1) {
        pk.h2[0] = __floats2half2_rn(acc1[0], acc1[1]);
        pk.h2[1] = __floats2half2_rn(acc1[2], acc1[3]);
        pk.h2[2] = __floats2half2_rn(acc1[4], acc1[5]);
        pk.h2[3] = __floats2half2_rn(acc1[6], acc1[7]);
        *reinterpret_cast<float4*>(H + (size_t)n1 * HIDDEN + j0) = pk.f4;
    }
    // attention scores (fp32 accumulators): head h = cg>>2
    float vs0 = 0.f, vd0 = 0.f, vs1 = 0.f, vd1 = 0.f;
    #pragma unroll
    for (int i = 0; i < 8; ++i) {
        float sa = a_src[j0 + i], da = a_dst[j0 + i];
        vs0 += acc0[i] * sa; vd0 += acc0[i] * da;
        vs1 += acc1[i] * sa; vd1 += acc1[i] * da;
    }
    vs0 += __shfl_xor(vs0, 1, 64); vs0 += __shfl_xor(vs0, 2, 64);
    vd0 += __shfl_xor(vd0, 1, 64); vd0 += __shfl_xor(vd0, 2, 64);
    vs1 += __shfl_xor(vs1, 1, 64); vs1 += __shfl_xor(vs1, 2, 64);
    vd1 += __shfl_xor(vd1, 1, 64); vd1 += __shfl_xor(vd1, 2, 64);
    if ((cg & 3) == 0) {
        int h = cg >> 2;
        if (ok0) { es[n0 * HEADS + h] = vs0; ed[n0 * HEADS + h] = vd0; }
        if (ok1) { es[n1 * HEADS + h] = vs1; ed[n1 * HEADS + h] = vd1; }
    }
}

// ---------------- per-node GAT aggregation (1 wave / node, fp16 gather) ----------------
__global__ void gat_aggregate_kernel(const __half* __restrict__ H, const float* __restrict__ es,
                                     const float* __restrict__ ed, const int* __restrict__ row_start,
                                     const int* __restrict__ csr_src, const float* __restrict__ bias,
                                     float* __restrict__ out) {
    int lane = threadIdx.x & 63;
    int n = blockIdx.x * 4 + (threadIdx.x >> 6);
    if (n >= N_NODES) return;
    int hid = lane >> 4;
    float edn = ed[n * HEADS + hid];
    int k0 = row_start[n], k1 = row_start[n + 1];
    const __half2* Hp = reinterpret_cast<const __half2*>(H);
    float dsum = 0.f, accx = 0.f, accy = 0.f;
    int k = k0;
    for (; k + 1 < k1; k += 2) {
        int s0 = csr_src[k];
        int s1 = csr_src[k + 1];
        float e0 = es[s0 * HEADS + hid] + edn;
        float e1 = es[s1 * HEADS + hid] + edn;
        __half2 h0 = Hp[(size_t)s0 * (HIDDEN / 2) + lane];
        __half2 h1 = Hp[(size_t)s1 * (HIDDEN / 2) + lane];
        e0 = (e0 > 0.f) ? e0 : (SLOPE * e0);
        e1 = (e1 > 0.f) ? e1 : (SLOPE * e1);
        float ex0 = __expf(e0);
        float ex1 = __expf(e1);
        float2 f0 = __half22float2(h0);
        float2 f1 = __half22float2(h1);
        dsum += ex0 + ex1;
        accx += ex0 * f0.x + ex1 * f1.x;
        accy += ex0 * f0.y + ex1 * f1.y;
    }
    if (k < k1) {
        int s0 = csr_src[k];
        float e0 = es[s0 * HEADS + hid] + edn;
        __half2 h0 = Hp[(size_t)s0 * (HIDDEN / 2) + lane];
        e0 = (e0 > 0.f) ? e0 : (SLOPE * e0);
        float ex0 = __expf(e0);
        float2 f0 = __half22float2(h0);
        dsum += ex0;
        accx += ex0 * f0.x;
        accy += ex0 * f0.y;
    }
    float inv = 1.f / (dsum + 1e-16f);
    int j = 2 * lane;
    out[(size_t)n * HIDDEN + j]     = accx * inv + bias[j];
    out[(size_t)n * HIDDEN + j + 1] = accy * inv + bias[j + 1];
}

// ---------------- BatchNorm (2-pass) + ELU ----------------
__global__ void bn_stats_kernel(const float* __restrict__ X, float* __restrict__ stats) {
    int c = threadIdx.x & 127;
    int r0 = blockIdx.x * 2 + (threadIdx.x >> 7);
    float s = 0.f, s2 = 0.f;
    for (int n = r0; n < N_NODES; n += gridDim.x * 2) {
        float v = X[(size_t)n * HIDDEN + c];
        s += v;
        s2 += v * v;
    }
    atomicAdd(&stats[c], s);
    atomicAdd(&stats[HIDDEN + c], s2);
}

__global__ void bn_apply_kernel(float* __restrict__ X, const float* __restrict__ stats,
                                const float* __restrict__ g, const float* __restrict__ b) {
    const float invN = 1.f / (float)N_NODES;
    int i = blockIdx.x * blockDim.x + threadIdx.x;
    const int total = N_NODES * HIDDEN;
    for (; i < total; i += gridDim.x * blockDim.x) {
        int c = i & 127;
        float mu = stats[c] * invN;
        float var = stats[HIDDEN + c] * invN - mu * mu;
        float v = (X[i] - mu) * rsqrtf(var + BN_EPS) * g[c] + b[c];
        X[i] = (v > 0.f) ? v : expm1f(v);
    }
}

// layer-2: BN+ELU fused into the pooling accumulation
__global__ void bn_apply_pool_kernel(const float* __restrict__ X, const float* __restrict__ stats,
                                     const float* __restrict__ g, const float* __restrict__ b,
                                     const int* __restrict__ batch,
                                     float* __restrict__ psum, float* __restrict__ pcnt) {
    const float invN = 1.f / (float)N_NODES;
    int i = blockIdx.x * blockDim.x + threadIdx.x;
    const int total = N_NODES * HIDDEN;
    for (; i < total; i += gridDim.x * blockDim.x) {
        int n = i >> 7, c = i & 127;
        float mu = stats[c] * invN;
        float var = stats[HIDDEN + c] * invN - mu * mu;
        float v = (X[i] - mu) * rsqrtf(var + BN_EPS) * g[c] + b[c];
        v = (v > 0.f) ? v : expm1f(v);
        int gidx = batch[n];
        atomicAdd(&psum[gidx * HIDDEN + c], v);
        if (c == 0) atomicAdd(&pcnt[gidx], 1.0f);
    }
}

// ---------------- final linear ----------------
__global__ void final_kernel(const float* __restrict__ psum, const float* __restrict__ pcnt,
                             const float* __restrict__ Wlin, const float* __restrict__ blin,
                             float* __restrict__ out) {
    int idx = blockIdx.x * blockDim.x + threadIdx.x;
    int g = idx >> 8, o = idx & 255;
    float invc = 1.f / fmaxf(pcnt[g], 1.f);
    float acc = blin[o];
    const float* pr = psum + g * HIDDEN;
    for (int j = 0; j < HIDDEN; ++j)
        acc += pr[j] * invc * Wlin[j * OUT_DIM + o];
    out[idx] = acc;
}

// ---------------- launch ----------------

extern "C" void kernel_launch(void* const* d_in, const int* in_sizes, int n_in,
                              void* d_out, int out_size, void* d_ws, size_t ws_size,
                              hipStream_t stream) {
    const float* x    = (const float*)d_in[0];
    const int*   ei   = (const int*)d_in[1];
    const int*   batch= (const int*)d_in[2];
    const float* W1   = (const float*)d_in[3];
    const float* as1  = (const float*)d_in[4];
    const float* ad1  = (const float*)d_in[5];
    const float* b1   = (const float*)d_in[6];
    const float* W2   = (const float*)d_in[7];
    const float* as2  = (const float*)d_in[8];
    const float* ad2  = (const float*)d_in[9];
    const float* b2   = (const float*)d_in[10];
    const float* bn1g = (const float*)d_in[11];
    const float* bn1b = (const float*)d_in[12];
    const float* bn2g = (const float*)d_in[13];
    const float* bn2b = (const float*)d_in[14];
    const float* Wlin = (const float*)d_in[15];
    const float* blin = (const float*)d_in[16];
    float* out = (float*)d_out;

    char* ws = (char*)d_ws;
    const size_t SZ_H = (size_t)N_NODES * HIDDEN * 4;
    __half* A       = (__half*)(ws);                      // fp16 H (12.8 MB used of 25.6)
    float* B        = (float*)(ws + SZ_H);
    size_t off = 2 * SZ_H;
    float* es       = (float*)(ws + off); off += (size_t)N_NODES * HEADS * 4;
    float* ed       = (float*)(ws + off); off += (size_t)N_NODES * HEADS * 4;
    int*   row_start= (int*)(ws + off);   off += ((size_t)(N_NODES + 1) * 4 + 511) & ~511ull;
    int*   csr_src  = (int*)(ws + off);   off += ((size_t)E_TOT * 4 + 511) & ~511ull;
    int*   tile_sums= (int*)(ws + off);   off += ((size_t)N_TILES * 4 + 511) & ~511ull;
    int*   tile_off = (int*)(ws + off);   off += ((size_t)N_TILES * 4 + 511) & ~511ull;
    size_t zoff = off;
    int*   deg      = (int*)(ws + off);   off += (size_t)N_NODES * 4;
    int*   cursor   = (int*)(ws + off);   off += (size_t)N_NODES * 4;
    float* stats1   = (float*)(ws + off); off += 2 * HIDDEN * 4;
    float* stats2   = (float*)(ws + off); off += 2 * HIDDEN * 4;
    float* psum     = (float*)(ws + off); off += (size_t)N_GRAPHS * HIDDEN * 4;
    float* pcnt     = (float*)(ws + off); off += (size_t)N_GRAPHS * 4;
    size_t zbytes = off - zoff;
    (void)ws_size; (void)n_in; (void)in_sizes; (void)out_size;

    hipMemsetAsync(ws + zoff, 0, zbytes, stream);

    const int TB = 256;
    const int egrid = (E_TOT + TB - 1) / TB;
    const int ggrid = (N_NODES + 31) / 32;

    // CSR build (shared by both layers)
    hist_kernel<<<egrid, TB, 0, stream>>>(ei, deg);
    scan_partial_kernel<<<N_TILES, TB, 0, stream>>>(deg, tile_sums);
    scan_tilesums_kernel<<<1, 64, 0, stream>>>(tile_sums, tile_off);
    scan_apply_kernel<<<N_TILES, TB, 0, stream>>>(deg, tile_off, row_start);
    scatter_kernel<<<egrid, TB, 0, stream>>>(ei, row_start, cursor, csr_src);

    // ---- layer 1 ----
    gemm_att_kernel<F_IN><<<ggrid, TB, 0, stream>>>(x, W1, as1, ad1, A, es, ed);
    gat_aggregate_kernel<<<N_NODES / 4, TB, 0, stream>>>(A, es, ed, row_start, csr_src, b1, B);
    bn_stats_kernel<<<512, TB, 0, stream>>>(B, stats1);
    bn_apply_kernel<<<2048, TB, 0, stream>>>(B, stats1, bn1g, bn1b);

    // ---- layer 2 ----
    gemm_att_kernel<HIDDEN><<<ggrid, TB, 0, stream>>>(B, W2, as2, ad2, A, es, ed);
    gat_aggregate_kernel<<<N_NODES / 4, TB, 0, stream>>>(A, es, ed, row_start, csr_src, b2, B);
    bn_stats_kernel<<<512, TB, 0, stream>>>(B, stats2);
    bn_apply_pool_kernel<<<2048, TB, 0, stream>>>(B, stats2, bn2g, bn2b, batch, psum, pcnt);

    // ---- final linear ----
    final_kernel<<<(N_GRAPHS * OUT_DIM) / TB, TB, 0, stream>>>(psum, pcnt, Wlin, blin, out);
}